// Round 1
// baseline (350.754 us; speedup 1.0000x reference)
//
#include <hip/hip_runtime.h>

#define HW_  16384   // H*W = 128*128
#define NPX  32768   // B*H*W

__device__ __forceinline__ float prelu_(float x, float a) { return x >= 0.f ? x : a * x; }

// ---------------- Kernel 1: x1 = prelu(conv1x1(x, w1, b1), a1) ----------------
// threads: 2*NPX ; tid>>15 selects output-channel half (32 of 64)
__global__ __launch_bounds__(256) void k_conv1(const float* __restrict__ x,
        const float* __restrict__ w1, const float* __restrict__ b1,
        const float* __restrict__ a1p, float* __restrict__ x1) {
    int tid = blockIdx.x * 256 + threadIdx.x;
    int px = tid & (NPX - 1);
    int half = tid >> 15;            // block-uniform
    int b = px >> 14, hw = px & (HW_ - 1);
    const float a1 = a1p[0];
    float xv[128];
    #pragma unroll
    for (int c = 0; c < 128; ++c) xv[c] = x[((b * 128 + c) << 14) + hw];
    for (int o2 = 0; o2 < 32; ++o2) {
        int o = half * 32 + o2;
        float acc = b1[o];
        #pragma unroll
        for (int c = 0; c < 128; ++c) acc = fmaf(w1[o * 128 + c], xv[c], acc);
        x1[((b * 64 + o) << 14) + hw] = prelu_(acc, a1);
    }
}

// ---------------- Kernel 2: f = relu(conv1x1(x1, wr, br)) ----------------
__global__ __launch_bounds__(256) void k_reduce(const float* __restrict__ x1,
        const float* __restrict__ wr, const float* __restrict__ br,
        float* __restrict__ f) {
    int px = blockIdx.x * 256 + threadIdx.x;
    int b = px >> 14, hw = px & (HW_ - 1);
    float v[64];
    #pragma unroll
    for (int c = 0; c < 64; ++c) v[c] = x1[((b * 64 + c) << 14) + hw];
    for (int j = 0; j < 32; ++j) {
        float acc = br[j];
        #pragma unroll
        for (int c = 0; c < 64; ++c) acc = fmaf(wr[j * 64 + c], v[c], acc);
        f[((b * 32 + j) << 14) + hw] = fmaxf(acc, 0.f);
    }
}

// ---------------- Kernel 3: fused span conv + involution -> x2 ----------------
// threads: 4*NPX ; tid>>15 = group g (4 groups x 16 channels)
__global__ __launch_bounds__(256) void k_invol(const float* __restrict__ x1,
        const float* __restrict__ f, const float* __restrict__ ws_,
        const float* __restrict__ bs, float* __restrict__ x2) {
    int tid = blockIdx.x * 256 + threadIdx.x;
    int px = tid & (NPX - 1);
    int g = tid >> 15;               // block-uniform
    int b = px >> 14, hw = px & (HW_ - 1);
    int h = hw >> 7, w = hw & 127;
    float fv[32];
    #pragma unroll
    for (int c = 0; c < 32; ++c) fv[c] = f[((b * 32 + c) << 14) + hw];
    float acc[16];
    #pragma unroll
    for (int u = 0; u < 16; ++u) acc[u] = 0.f;
    for (int kk = 0; kk < 49; ++kk) {
        int o = g * 49 + kk;
        float kwv = bs[o];
        #pragma unroll
        for (int c = 0; c < 32; ++c) kwv = fmaf(ws_[o * 32 + c], fv[c], kwv);
        int hh = h + (kk / 7) - 3;
        int ww = w + (kk % 7) - 3;
        if (hh >= 0 && hh < 128 && ww >= 0 && ww < 128) {
            int base = ((b * 64 + g * 16) << 14) + (hh << 7) + ww;
            #pragma unroll
            for (int u = 0; u < 16; ++u)
                acc[u] = fmaf(kwv, x1[base + (u << 14)], acc[u]);
        }
    }
    #pragma unroll
    for (int u = 0; u < 16; ++u)
        x2[((b * 64 + g * 16 + u) << 14) + hw] = acc[u];
}

// ---------------- Kernel 4: ZPool (max & mean over 32 ch of f) ----------------
__global__ __launch_bounds__(256) void k_zpool(const float* __restrict__ f,
                                               float* __restrict__ zp) {
    int px = blockIdx.x * 256 + threadIdx.x;
    int b = px >> 14, hw = px & (HW_ - 1);
    float mx = -1e30f, sm = 0.f;
    #pragma unroll
    for (int c = 0; c < 32; ++c) {
        float v = f[((b * 32 + c) << 14) + hw];
        mx = fmaxf(mx, v);
        sm += v;
    }
    zp[((b * 2 + 0) << 14) + hw] = mx;
    zp[((b * 2 + 1) << 14) + hw] = sm * (1.f / 32.f);
}

// ---------------- Kernel 5: attn = sigmoid(conv7x7(zp, wa, ba)) ----------------
__global__ __launch_bounds__(256) void k_attn(const float* __restrict__ zp,
        const float* __restrict__ wa, const float* __restrict__ ba,
        float* __restrict__ attn) {
    int px = blockIdx.x * 256 + threadIdx.x;
    int b = px >> 14, hw = px & (HW_ - 1);
    int h = hw >> 7, w = hw & 127;
    float acc = ba[0];
    for (int c = 0; c < 2; ++c)
        for (int i = 0; i < 7; ++i) {
            int hh = h + i - 3;
            if (hh < 0 || hh >= 128) continue;
            for (int j = 0; j < 7; ++j) {
                int ww = w + j - 3;
                if (ww < 0 || ww >= 128) continue;
                acc = fmaf(wa[c * 49 + i * 7 + j], zp[((b * 2 + c) << 14) + (hh << 7) + ww], acc);
            }
        }
    attn[px] = 1.f / (1.f + expf(-acc));
}

// ---------------- Kernel 6: p1 = prelu(conv3x3(f, wp1, bp1), ap) ----------------
// threads: 2*NPX ; tid>>15 = output-channel half (16 of 32)
__global__ __launch_bounds__(256) void k_psec1(const float* __restrict__ f,
        const float* __restrict__ wp1, const float* __restrict__ bp1,
        const float* __restrict__ app, float* __restrict__ p1) {
    int tid = blockIdx.x * 256 + threadIdx.x;
    int px = tid & (NPX - 1);
    int half = tid >> 15;            // block-uniform
    int b = px >> 14, hw = px & (HW_ - 1);
    int h = hw >> 7, w = hw & 127;
    const float ap = app[0];
    float acc[16];
    #pragma unroll
    for (int u = 0; u < 16; ++u) acc[u] = bp1[half * 16 + u];
    for (int ci = 0; ci < 32; ++ci) {
        float fv[9];
        #pragma unroll
        for (int i = 0; i < 3; ++i)
            #pragma unroll
            for (int j = 0; j < 3; ++j) {
                int hh = h + i - 1, ww = w + j - 1;
                fv[i * 3 + j] = (hh >= 0 && hh < 128 && ww >= 0 && ww < 128)
                                    ? f[((b * 32 + ci) << 14) + (hh << 7) + ww] : 0.f;
            }
        #pragma unroll
        for (int u = 0; u < 16; ++u) {
            int co = half * 16 + u;
            #pragma unroll
            for (int k = 0; k < 9; ++k)
                acc[u] = fmaf(wp1[(co * 32 + ci) * 9 + k], fv[k], acc[u]);
        }
    }
    #pragma unroll
    for (int u = 0; u < 16; ++u)
        p1[((b * 32 + half * 16 + u) << 14) + hw] = prelu_(acc[u], ap);
}

// ---------------- Kernel 7: out = conv2(prelu(x2,a2))*attn + wp2*p1 ----------------
// threads: 4*NPX ; tid>>15 = output-channel quarter (32 of 128)
__global__ __launch_bounds__(256) void k_final(const float* __restrict__ x2,
        const float* __restrict__ p1, const float* __restrict__ attn,
        const float* __restrict__ a2p, const float* __restrict__ w2,
        const float* __restrict__ b2, const float* __restrict__ wp2,
        const float* __restrict__ bp2, float* __restrict__ out) {
    int tid = blockIdx.x * 256 + threadIdx.x;
    int px = tid & (NPX - 1);
    int q = tid >> 15;               // block-uniform
    int b = px >> 14, hw = px & (HW_ - 1);
    const float a2 = a2p[0];
    float xv[64];
    #pragma unroll
    for (int c = 0; c < 64; ++c) xv[c] = prelu_(x2[((b * 64 + c) << 14) + hw], a2);
    float pv[32];
    #pragma unroll
    for (int c = 0; c < 32; ++c) pv[c] = p1[((b * 32 + c) << 14) + hw];
    float at = attn[px];
    for (int o2 = 0; o2 < 32; ++o2) {
        int o = q * 32 + o2;
        float acc = b2[o];
        #pragma unroll
        for (int c = 0; c < 64; ++c) acc = fmaf(w2[o * 64 + c], xv[c], acc);
        float ps = bp2[o];
        #pragma unroll
        for (int c = 0; c < 32; ++c) ps = fmaf(wp2[o * 32 + c], pv[c], ps);
        out[((b * 128 + o) << 14) + hw] = acc * at + ps;
    }
}

extern "C" void kernel_launch(void* const* d_in, const int* in_sizes, int n_in,
                              void* d_out, int out_size, void* d_ws, size_t ws_size,
                              hipStream_t stream) {
    const float* x   = (const float*)d_in[0];
    const float* w1  = (const float*)d_in[1];
    const float* b1  = (const float*)d_in[2];
    const float* a1  = (const float*)d_in[3];
    const float* wr  = (const float*)d_in[4];
    const float* br  = (const float*)d_in[5];
    const float* ws_ = (const float*)d_in[6];
    const float* bs  = (const float*)d_in[7];
    const float* a2  = (const float*)d_in[8];
    const float* w2  = (const float*)d_in[9];
    const float* b2  = (const float*)d_in[10];
    const float* wa  = (const float*)d_in[11];
    const float* ba  = (const float*)d_in[12];
    const float* wp1 = (const float*)d_in[13];
    const float* bp1 = (const float*)d_in[14];
    const float* ap  = (const float*)d_in[15];
    const float* wp2 = (const float*)d_in[16];
    const float* bp2 = (const float*)d_in[17];
    float* out = (float*)d_out;

    // workspace layout (floats)
    float* w = (float*)d_ws;
    float* ws_x1   = w;                        // 2*64*16384  = 2,097,152
    float* ws_f    = ws_x1 + 2 * 64 * HW_;     // 2*32*16384  = 1,048,576
    float* ws_x2   = ws_f  + 2 * 32 * HW_;     // 2*64*16384  = 2,097,152
    float* ws_zp   = ws_x2 + 2 * 64 * HW_;     // 2*2*16384   = 65,536
    float* ws_attn = ws_zp + 2 * 2 * HW_;      // 2*16384     = 32,768
    float* ws_p1   = ws_attn + NPX;            // 2*32*16384  = 1,048,576

    hipLaunchKernelGGL(k_conv1, dim3(2 * NPX / 256), dim3(256), 0, stream,
                       x, w1, b1, a1, ws_x1);
    hipLaunchKernelGGL(k_reduce, dim3(NPX / 256), dim3(256), 0, stream,
                       ws_x1, wr, br, ws_f);
    hipLaunchKernelGGL(k_invol, dim3(4 * NPX / 256), dim3(256), 0, stream,
                       ws_x1, ws_f, ws_, bs, ws_x2);
    hipLaunchKernelGGL(k_zpool, dim3(NPX / 256), dim3(256), 0, stream,
                       ws_f, ws_zp);
    hipLaunchKernelGGL(k_attn, dim3(NPX / 256), dim3(256), 0, stream,
                       ws_zp, wa, ba, ws_attn);
    hipLaunchKernelGGL(k_psec1, dim3(2 * NPX / 256), dim3(256), 0, stream,
                       ws_f, wp1, bp1, ap, ws_p1);
    hipLaunchKernelGGL(k_final, dim3(4 * NPX / 256), dim3(256), 0, stream,
                       ws_x2, ws_p1, ws_attn, a2, w2, b2, wp2, bp2, out);
}